// Round 1
// 164.873 us; speedup vs baseline: 1.0554x; 1.0554x over previous
//
#include <hip/hip_runtime.h>
#include <cstdint>

#define BLOCK_SIZE 256
#define NPOS 63   // 9*7 spatial positions per batch

typedef __attribute__((ext_vector_type(8))) _Float16 f16x8;     // 8 f16, 4 VGPRs
typedef __attribute__((ext_vector_type(4))) float f32x4;
typedef __attribute__((ext_vector_type(4))) unsigned int uint4v;

// f32 -> f16 RNE bits (low 16) — v_cvt_f16_f32 (default RNE)
__device__ __forceinline__ unsigned rne_f16(float a) {
    _Float16 h = (_Float16)a;
    return (unsigned)__builtin_bit_cast(unsigned short, h);
}
// pack two f32 -> 2 f16 RTZ in ONE v_cvt_pkrtz_f16_f32 (short0=a, short1=b)
__device__ __forceinline__ unsigned pack_f16(float a, float b) {
    auto t = __builtin_amdgcn_cvt_pkrtz(a, b);
    return __builtin_bit_cast(unsigned, t);
}

// R14 -> R15: SINGLE-PRODUCT F16. W2 rounded once to f16 RNE (2^-12 rel,
// 8x tighter than R14's bf16 2^-9); h1 packed with v_cvt_pkrtz (2^-11 rel).
// Expected out error ~1e-3, under the 0.0078 floor R14 already passed at.
//  - MFMA/wave 64 -> 32, h1-pack VALU per i-tile 96 -> ~56 (no Dekker split)
//  - adj bitmask via one coalesced lane-load + __ballot (kills 45-iter loop)
//  - i-loop unroll 1 -> 2: fragments halved (8 VGPR/i) so two independent
//    tile chains fit; overlaps shfl/h1-build/LDS/MFMA latency chains.
// Everything else (phase-1 wave-per-batch, swizzled LDS, operand-swapped
// MFMA, channel-major epilogue) is R13/R14-proven code unchanged.
__global__ __launch_bounds__(BLOCK_SIZE) void carnet_fused(
    const float* __restrict__ x,      // (B, 9, 7) flat
    const int*   __restrict__ adj,    // (B, 45)
    const float* __restrict__ ctx,    // (B, 45)
    const float* __restrict__ gcn_W,  // (7, 7)
    const float* __restrict__ gcn_b,  // (7)
    const float* __restrict__ ctx_W,  // (45, 63)
    const float* __restrict__ ctx_b,  // (63)
    const float* __restrict__ W1,     // (64, 2)
    const float* __restrict__ b1,     // (64)
    const float* __restrict__ W2,     // (64, 64)
    const float* __restrict__ b2,     // (64)
    const float* __restrict__ W3,     // (2, 64)
    const float* __restrict__ b3,     // (2)
    float* __restrict__ out)          // (B, 2, 9, 7) flat
{
    __shared__ short sh2b[64 * 64];   // 8192 B, XOR-swizzled, RNE f16 of W2

    const int t    = threadIdx.x;
    const int lane = t & 63;

    // ---- staging: W2 fp32 -> RNE f16 plane, swizzled LDS write ----
    {
        const int r  = t >> 2;
        const int cq = t & 3;
        const float* wsrc = W2 + r * 64 + cq * 16;
        const float4 w0 = ((const float4*)wsrc)[0];
        const float4 w1 = ((const float4*)wsrc)[1];
        const float4 w2v = ((const float4*)wsrc)[2];
        const float4 w3v = ((const float4*)wsrc)[3];
        uint4v hA = { rne_f16(w0.x)  | (rne_f16(w0.y)  << 16),
                      rne_f16(w0.z)  | (rne_f16(w0.w)  << 16),
                      rne_f16(w1.x)  | (rne_f16(w1.y)  << 16),
                      rne_f16(w1.z)  | (rne_f16(w1.w)  << 16) };
        uint4v hB = { rne_f16(w2v.x) | (rne_f16(w2v.y) << 16),
                      rne_f16(w2v.z) | (rne_f16(w2v.w) << 16),
                      rne_f16(w3v.x) | (rne_f16(w3v.y) << 16),
                      rne_f16(w3v.z) | (rne_f16(w3v.w) << 16) };
        const int sA = ((2 * cq)     ^ (r & 7)) * 8;
        const int sB = ((2 * cq + 1) ^ (r & 7)) * 8;
        *(uint4v*)&sh2b[r * 64 + sA] = hA;
        *(uint4v*)&sh2b[r * 64 + sB] = hB;
    }

    // ================= PHASE 1: z, c (R10-proven, wave = batch) ==========
    const int b = __builtin_amdgcn_readfirstlane(blockIdx.x * 4 + (t >> 6));
    const int p = lane < 63 ? lane : 62;
    const int n = p / 7;
    const int f = p - n * 7;

    // adjacency bitmask: one coalesced lane-load + ballot (bit i = adj[i]!=0)
    const int* ab = adj + b * 45;
    int aval = 0;
    if (lane < 45) aval = ab[lane];
    const uint64_t am = __ballot(aval != 0);

    float d[9];
#pragma unroll
    for (int i = 0; i < 9; ++i) {
        const int s = 9 * i - (i * (i - 1)) / 2;
        const int w = 8 - i;
        const uint64_t bits = (am >> (s + 1)) & ((1ull << w) - 1ull);
        d[i] = __frsqrt_rn((float)(1 + __popcll(bits)));
    }

    const float* xb = x + b * 63;
    float yv = 0.f;
#pragma unroll
    for (int k = 0; k < 7; ++k)
        yv = fmaf(xb[n * 7 + k], gcn_W[k * 7 + f], yv);

    float zt = 0.f;
    const int snn = 9 * n - (n * (n - 1)) / 2 - n;
#pragma unroll
    for (int m = 0; m < 9; ++m) {
        const float ym = __shfl(yv, m * 7 + f);
        int sh = snn + m;
        sh = sh < 0 ? 0 : sh;
        const bool conn = (m == n) || ((m > n) && ((am >> sh) & 1ull));
        zt = fmaf(conn ? d[m] : 0.f, ym, zt);
    }
    const float zv = fmaf(d[n], zt, gcn_b[f]);

    // ctx dot with 4 accumulators (shorter dependency chain)
    const float* cb = ctx + b * 45;
    float ca0 = ctx_b[p], ca1 = 0.f, ca2 = 0.f, ca3 = 0.f;
#pragma unroll
    for (int q = 0; q < 44; q += 4) {
        ca0 = fmaf(cb[q],     ctx_W[q * 63 + p],       ca0);
        ca1 = fmaf(cb[q + 1], ctx_W[(q + 1) * 63 + p], ca1);
        ca2 = fmaf(cb[q + 2], ctx_W[(q + 2) * 63 + p], ca2);
        ca3 = fmaf(cb[q + 3], ctx_W[(q + 3) * 63 + p], ca3);
    }
    ca0 = fmaf(cb[44], ctx_W[44 * 63 + p], ca0);
    const float cvv = fmaxf((ca0 + ca1) + (ca2 + ca3), 0.f);

    // ================= PHASE 2: MFMA (operand-swapped, f16 single) =======
    const int cl   = lane & 15;       // position within i-tile (B-operand n)
    const int quad = lane >> 4;       // k-octet / C row group (channel)
    const int s0 = (quad ^ (cl & 7)) * 16;

    float2 wp0[8], wp1[8];
    float  bb0[8], bb1[8];
#pragma unroll
    for (int j = 0; j < 8; ++j) {
        const int o = quad * 8 + j;
        wp0[j] = *(const float2*)(W1 + 2 * o);
        bb0[j] = b1[o];
        wp1[j] = *(const float2*)(W1 + 2 * (o + 32));
        bb1[j] = b1[o + 32];
    }

    const float4 b2q0 = *(const float4*)(b2 + quad * 4);
    const float4 b2q1 = *(const float4*)(b2 + 16 + quad * 4);
    const float4 b2q2 = *(const float4*)(b2 + 32 + quad * 4);
    const float4 b2q3 = *(const float4*)(b2 + 48 + quad * 4);
    const float4 wa0 = *(const float4*)(W3 + quad * 4);
    const float4 wa1 = *(const float4*)(W3 + 16 + quad * 4);
    const float4 wa2 = *(const float4*)(W3 + 32 + quad * 4);
    const float4 wa3 = *(const float4*)(W3 + 48 + quad * 4);
    const float4 wb0 = *(const float4*)(W3 + 64 + quad * 4);
    const float4 wb1 = *(const float4*)(W3 + 80 + quad * 4);
    const float4 wb2 = *(const float4*)(W3 + 96 + quad * 4);
    const float4 wb3 = *(const float4*)(W3 + 112 + quad * 4);
    const float b30 = b3[0], b31 = b3[1];
    float* __restrict__ ob = out + b * 126;

    const char* sh2bB = (const char*)sh2b;

    __syncthreads();   // staging complete before first B read

#pragma unroll 2
    for (int i = 0; i < 4; ++i) {
        const float zm = __shfl(zv,  i * 16 + cl);
        const float cm = __shfl(cvv, i * 16 + cl);

        // h1 fragments (MFMA B operand): single f16 product, cvt_pkrtz packs
        uint4v ph0, ph1;
#pragma unroll
        for (int jj = 0; jj < 4; ++jj) {
            float ha = fmaxf(fmaf(wp0[2*jj].x,   zm, fmaf(wp0[2*jj].y,   cm, bb0[2*jj])),   0.f);
            float hb = fmaxf(fmaf(wp0[2*jj+1].x, zm, fmaf(wp0[2*jj+1].y, cm, bb0[2*jj+1])), 0.f);
            ph0[jj] = pack_f16(ha, hb);

            ha = fmaxf(fmaf(wp1[2*jj].x,   zm, fmaf(wp1[2*jj].y,   cm, bb1[2*jj])),   0.f);
            hb = fmaxf(fmaf(wp1[2*jj+1].x, zm, fmaf(wp1[2*jj+1].y, cm, bb1[2*jj+1])), 0.f);
            ph1[jj] = pack_f16(ha, hb);
        }
        const f16x8 ah0 = __builtin_bit_cast(f16x8, ph0);
        const f16x8 ah1 = __builtin_bit_cast(f16x8, ph1);

        f32x4 acc0 = {b2q0.x, b2q0.y, b2q0.z, b2q0.w};
        f32x4 acc1 = {b2q1.x, b2q1.y, b2q1.z, b2q1.w};
        f32x4 acc2 = {b2q2.x, b2q2.y, b2q2.z, b2q2.w};
        f32x4 acc3 = {b2q3.x, b2q3.y, b2q3.z, b2q3.w};

        // A = W2 f16 frag (LDS, 2 reads/STEP), B = h1 f16 (2 MFMAs/STEP).
#define STEP(nt) {                                                                    \
        int bo = cl * 128 + s0;                                                       \
        asm volatile("" : "+v"(bo));                                                  \
        const int bo2 = (cl * 128) | (s0 ^ 64);                                       \
        const f16x8 wf0 = *(const f16x8*)(sh2bB + bo  + ((nt) * 2048));               \
        const f16x8 wf1 = *(const f16x8*)(sh2bB + bo2 + ((nt) * 2048));               \
        acc##nt = __builtin_amdgcn_mfma_f32_16x16x32_f16(wf0, ah0, acc##nt, 0, 0, 0); \
        acc##nt = __builtin_amdgcn_mfma_f32_16x16x32_f16(wf1, ah1, acc##nt, 0, 0, 0); }
        STEP(0) STEP(1) STEP(2) STEP(3)
#undef STEP

        // Epilogue (channel-major, R13-proven): register-local relu + W3 dot,
        // then sum over 4 quads via shfl_xor(16/32); quad 0 stores.
        float q0, q1;
        {
            float h;
            h = fmaxf(acc0[0], 0.f); q0 = h * wa0.x;            q1 = h * wb0.x;
            h = fmaxf(acc0[1], 0.f); q0 = fmaf(h, wa0.y, q0);   q1 = fmaf(h, wb0.y, q1);
            h = fmaxf(acc0[2], 0.f); q0 = fmaf(h, wa0.z, q0);   q1 = fmaf(h, wb0.z, q1);
            h = fmaxf(acc0[3], 0.f); q0 = fmaf(h, wa0.w, q0);   q1 = fmaf(h, wb0.w, q1);
            h = fmaxf(acc1[0], 0.f); q0 = fmaf(h, wa1.x, q0);   q1 = fmaf(h, wb1.x, q1);
            h = fmaxf(acc1[1], 0.f); q0 = fmaf(h, wa1.y, q0);   q1 = fmaf(h, wb1.y, q1);
            h = fmaxf(acc1[2], 0.f); q0 = fmaf(h, wa1.z, q0);   q1 = fmaf(h, wb1.z, q1);
            h = fmaxf(acc1[3], 0.f); q0 = fmaf(h, wa1.w, q0);   q1 = fmaf(h, wb1.w, q1);
            h = fmaxf(acc2[0], 0.f); q0 = fmaf(h, wa2.x, q0);   q1 = fmaf(h, wb2.x, q1);
            h = fmaxf(acc2[1], 0.f); q0 = fmaf(h, wa2.y, q0);   q1 = fmaf(h, wb2.y, q1);
            h = fmaxf(acc2[2], 0.f); q0 = fmaf(h, wa2.z, q0);   q1 = fmaf(h, wb2.z, q1);
            h = fmaxf(acc2[3], 0.f); q0 = fmaf(h, wa2.w, q0);   q1 = fmaf(h, wb2.w, q1);
            h = fmaxf(acc3[0], 0.f); q0 = fmaf(h, wa3.x, q0);   q1 = fmaf(h, wb3.x, q1);
            h = fmaxf(acc3[1], 0.f); q0 = fmaf(h, wa3.y, q0);   q1 = fmaf(h, wb3.y, q1);
            h = fmaxf(acc3[2], 0.f); q0 = fmaf(h, wa3.z, q0);   q1 = fmaf(h, wb3.z, q1);
            h = fmaxf(acc3[3], 0.f); q0 = fmaf(h, wa3.w, q0);   q1 = fmaf(h, wb3.w, q1);
        }
        q0 += __shfl_xor(q0, 16); q0 += __shfl_xor(q0, 32);
        q1 += __shfl_xor(q1, 16); q1 += __shfl_xor(q1, 32);

        const int pp = i * 16 + cl;
        if (quad == 0 && pp < NPOS) {
            ob[pp]        = q0 + b30;
            ob[NPOS + pp] = q1 + b31;
        }
    }
}

extern "C" void kernel_launch(void* const* d_in, const int* in_sizes, int n_in,
                              void* d_out, int out_size, void* d_ws, size_t ws_size,
                              hipStream_t stream) {
    const float* x     = (const float*)d_in[0];
    const int*   adj   = (const int*)  d_in[1];
    const float* ctx   = (const float*)d_in[2];
    const float* gcn_W = (const float*)d_in[3];
    const float* gcn_b = (const float*)d_in[4];
    const float* ctx_W = (const float*)d_in[5];
    const float* ctx_b = (const float*)d_in[6];
    const float* W1    = (const float*)d_in[7];
    const float* b1    = (const float*)d_in[8];
    const float* W2    = (const float*)d_in[9];
    const float* b2    = (const float*)d_in[10];
    const float* W3    = (const float*)d_in[11];
    const float* b3    = (const float*)d_in[12];
    float* out = (float*)d_out;

    const int nbatch = in_sizes[1] / 45;            // B = 32768
    const int grid = (nbatch + 3) / 4;              // 4 batches (waves) per block
    carnet_fused<<<grid, BLOCK_SIZE, 0, stream>>>(
        x, adj, ctx, gcn_W, gcn_b, ctx_W, ctx_b,
        W1, b1, W2, b2, W3, b3, out);
}